// Round 10
// baseline (146.538 us; speedup 1.0000x reference)
//
#include <hip/hip_runtime.h>

// FANS: B=131072 rows x 16 states, MLP 12->64->64->1 with tanh, fp32 in/out.
// R10 = R9 with CHUNK 8->4 (grid (128,16) = 2048 blocks = 8 blocks/CU).
// R9 landed: 83.5us, VGPR=64, VALU 60%, occ 31%. VGPR=64 sits EXACTLY at the
// 8-waves/SIMD boundary; occupancy was grid-limited (1024 blocks = 4/CU), not
// register-limited. R8's failure was launch_bounds(256,8) FORCING allocation
// to 32 regs; launch_bounds(256,4) + natural 64-reg allocation permits 8
// resident blocks/CU without a squeeze. LDS 8 x 17.4KB = 139KB < 160KB.
// Kept: f16 MFMA both layers; 2*log2(e) folded into W0/W1 frags; "1-2r"
// folded into W2 dot; z via register pack + 2x ds_write_b128; Hd stride 36.
// No __syncthreads: every LDS row is written and read by the same wave.

#define N_STATES 16
#define CHUNK    4
#define TANH_SCALE 2.885390081777927f   // 2*log2(e)

typedef _Float16 f16x8 __attribute__((ext_vector_type(8)));
typedef float    f32x4 __attribute__((ext_vector_type(4)));

__device__ __forceinline__ unsigned int pack_f16(float a, float b) {
    auto p = __builtin_amdgcn_cvt_pkrtz(a, b);          // __fp16 ext_vector(2)
    union { decltype(p) h; unsigned int u; } cv{p};
    return cv.u;
}

// input ps = 2*log2(e)*x (pre-scaled via weight fold); r = 1/(e^{2x}+1),
// tanh(x) = 1 - 2r.
__device__ __forceinline__ float sig_r(float ps) {
    float e = __builtin_amdgcn_exp2f(ps);
    return __builtin_amdgcn_rcpf(e + 1.0f);
}
__device__ __forceinline__ float tanh_from_scaled(float ps) {
    return __builtin_fmaf(-2.0f, sig_r(ps), 1.0f);
}

__global__ __launch_bounds__(256, 4) void fans_mfma_kernel(
    const float* __restrict__ x_f, const float* __restrict__ x_b,
    const float* __restrict__ u,   const float* __restrict__ W0,
    const float* __restrict__ W1,  const float* __restrict__ W2,
    float* __restrict__ out)
{
    // z planes: plane q (0/1) holds dwords [4q..4q+3] of each row's 16 f16.
    __shared__ __align__(16) uint4 zpl[2 * 256];               // 8 KB
    // H^T pair-packed, row stride 36 dwords (144B).
    __shared__ __align__(16) unsigned int Hd[4][16][36];       // 9 KB

    const int s   = blockIdx.y;
    const int tid = threadIdx.x;
    const int b0  = blockIdx.x * (256 * CHUNK);

    const int lid = tid & 63;
    const int w   = tid >> 6;     // wave id; wave w owns local rows [64w,64w+64)
    const int c   = lid & 15;
    const int q   = lid >> 4;

    // ---------------- weight fragments (once per block) ----------------
    // Layer1 A-frag: A[m = feat 16t+c][k = 8q+j] = W0[s][feat][k] * SCALE
    f16x8 a0[4];
    {
        const float* w0s = W0 + s * 768;
        #pragma unroll
        for (int t = 0; t < 4; ++t) {
            #pragma unroll
            for (int j = 0; j < 8; ++j) {
                const int k = 8 * q + j;
                const float v = (k < 12) ? w0s[(16 * t + c) * 12 + k] * TANH_SCALE : 0.0f;
                a0[t][j] = (_Float16)v;
            }
        }
    }
    // Layer2 A-frag: A[m = feat_out 16t+c][k = 32ks+8q+j] = W1[s][o][h] * SCALE
    f16x8 a1[2][4];
    {
        const float* w1s = W1 + s * 4096;
        #pragma unroll
        for (int ks = 0; ks < 2; ++ks) {
            #pragma unroll
            for (int t = 0; t < 4; ++t) {
                const float4* p = (const float4*)(w1s + (16 * t + c) * 64 + 32 * ks + 8 * q);
                const float4 v0 = p[0], v1 = p[1];
                a1[ks][t] = (f16x8){(_Float16)(v0.x * TANH_SCALE), (_Float16)(v0.y * TANH_SCALE),
                                    (_Float16)(v0.z * TANH_SCALE), (_Float16)(v0.w * TANH_SCALE),
                                    (_Float16)(v1.x * TANH_SCALE), (_Float16)(v1.y * TANH_SCALE),
                                    (_Float16)(v1.z * TANH_SCALE), (_Float16)(v1.w * TANH_SCALE)};
            }
        }
    }
    // W2 fold: dx = sum(w2) + sum_o r_o * (-2*w2_o). Lane holds feats 16t+4q+r.
    float w2n[16];
    float sumw2 = 0.0f;
    {
        const float* w2s = W2 + s * 64;
        #pragma unroll
        for (int t = 0; t < 4; ++t)
            #pragma unroll
            for (int r = 0; r < 4; ++r) {
                const float v = w2s[16 * t + 4 * q + r];
                w2n[4 * t + r] = -2.0f * v;
                sumw2 += v;
            }
    }

    const int wrap = (s > 8) ? (s - 8) : 0;   // IDX[s] = {0..wrap-1}++{s..15}

    #pragma unroll 1
    for (int ch = 0; ch < CHUNK; ++ch) {
        const int rbase = b0 + ch * 256;

        // ---- phase 1: gather z for own row, pack, 2x b128 into planes ----
        {
            const int row = rbase + tid;
            float zs[8];
            #pragma unroll
            for (int j = 0; j < 8; ++j) {
                const int idx = (j < wrap) ? j : (s + j - wrap);  // uniform
                zs[j] = (idx < 8) ? x_f[row * 8 + idx] : x_b[row * 8 + (idx - 8)];
            }
            const float4 uv = *(const float4*)(u + row * 4);
            zpl[tid] = make_uint4(pack_f16(zs[0], zs[1]), pack_f16(zs[2], zs[3]),
                                  pack_f16(zs[4], zs[5]), pack_f16(zs[6], zs[7]));
            zpl[256 + tid] = make_uint4(pack_f16(uv.x, uv.y), pack_f16(uv.z, uv.w), 0u, 0u);
        }

        // ---- phase 2: 4 M-tiles of 16 rows (own wave's rows only) ----
        #pragma unroll
        for (int m = 0; m < 4; ++m) {
            const int rowb = 64 * w + 16 * m;

            // z B-frag: B[k = 8q+j][n = row c]; quads 2,3 are zero (K pad)
            f16x8 zf = {0, 0, 0, 0, 0, 0, 0, 0};
            if (q < 2) {
                const uint4 zv = zpl[q * 256 + rowb + c];
                union { uint4 v; f16x8 h; } cz{zv};
                zf = cz.h;
            }

            // layer 1: C[row = feat 16t+4q+r][col = batch row c], pre-scaled
            f32x4 c1[4];
            #pragma unroll
            for (int t = 0; t < 4; ++t)
                c1[t] = __builtin_amdgcn_mfma_f32_16x16x32_f16(
                    a0[t], zf, (f32x4){0.f, 0.f, 0.f, 0.f}, 0, 0, 0);

            // tanh -> pack -> LDS: dword P = 8t+2q holds feats (16t+4q, +1)
            #pragma unroll
            for (int t = 0; t < 4; ++t) {
                *(uint2*)&Hd[w][c][8 * t + 2 * q] =
                    make_uint2(pack_f16(tanh_from_scaled(c1[t][0]), tanh_from_scaled(c1[t][1])),
                               pack_f16(tanh_from_scaled(c1[t][2]), tanh_from_scaled(c1[t][3])));
            }

            // layer 2: B-frag[k = 32ks+8q+j][n = c] = dwords 16ks+4q+0..3
            f32x4 c2[4] = {{0.f, 0.f, 0.f, 0.f}, {0.f, 0.f, 0.f, 0.f},
                           {0.f, 0.f, 0.f, 0.f}, {0.f, 0.f, 0.f, 0.f}};
            #pragma unroll
            for (int ks = 0; ks < 2; ++ks) {
                const uint4 hv = *(const uint4*)&Hd[w][c][16 * ks + 4 * q];
                union { uint4 v; f16x8 h; } bb{hv};
                #pragma unroll
                for (int t = 0; t < 4; ++t)
                    c2[t] = __builtin_amdgcn_mfma_f32_16x16x32_f16(a1[ks][t], bb.h, c2[t], 0, 0, 0);
            }

            // layer 3: acc = sum(w2) + sum_o r_o * (-2 w2_o); reduce over quads
            float acc = sumw2;
            #pragma unroll
            for (int t = 0; t < 4; ++t)
                #pragma unroll
                for (int r = 0; r < 4; ++r)
                    acc = __builtin_fmaf(sig_r(c2[t][r]), w2n[4 * t + r], acc);
            acc += __shfl_xor(acc, 16);
            acc += __shfl_xor(acc, 32);

            if (lid < 16)
                out[(rbase + rowb + lid) * N_STATES + s] = acc;
        }
    }
}

extern "C" void kernel_launch(void* const* d_in, const int* in_sizes, int n_in,
                              void* d_out, int out_size, void* d_ws, size_t ws_size,
                              hipStream_t stream) {
    const float* x_f = (const float*)d_in[0];
    const float* x_b = (const float*)d_in[1];
    const float* u   = (const float*)d_in[2];
    const float* W0  = (const float*)d_in[3];
    const float* W1  = (const float*)d_in[4];
    const float* W2  = (const float*)d_in[5];
    float* out = (float*)d_out;

    const int nb = in_sizes[0] / 8;                 // 131072 = 128 * 1024
    dim3 grid(nb / (256 * CHUNK), N_STATES);        // (128, 16) = 2048 blocks
    fans_mfma_kernel<<<grid, 256, 0, stream>>>(x_f, x_b, u, W0, W1, W2, out);
}

// Round 11
// 138.021 us; speedup vs baseline: 1.0617x; 1.0617x over previous
//
#include <hip/hip_runtime.h>

// FANS: B=131072 rows x 16 states, MLP 12->64->64->1 with tanh, fp32 in/out.
// R11: register diet. R10 falsified grid-limited-occupancy: residency is
// hard-capped at 4 blocks/CU because unified VGPR+AGPR = 64 arch + 64 AGPR
// (a0 16 + a1 32 + accums 16) = 128/wave -> 4 waves/SIMD. (Also explains R8:
// launch_bounds(256,8) = 64-unified budget vs 128 need -> spill.)
// Fix: W0/W1 fragments live in LDS in fragment-ready [plane][lane] layout
// (lane stride 16B -> stride-1 b128 reads, 2-way bank aliasing = free),
// staged once by wave 0 (frags identical across waves) + one __syncthreads.
// Unified drops to ~80 -> 6 waves/SIMD; LDS 25.6KB -> 6 blocks/CU (153.6<160).
// launch_bounds(256,5): reg cap 102, ~20 slack over need (no R8 squeeze).
// Kept: f16 MFMA both layers, tanh folds (scale into frags, 1-2r into W2 dot),
// zpl (plane1 trimmed to uint2), Hd stride 36, per-wave LDS privacy.

#define N_STATES 16
#define CHUNK    4
#define TANH_SCALE 2.885390081777927f   // 2*log2(e)

typedef _Float16 f16x8 __attribute__((ext_vector_type(8)));
typedef float    f32x4 __attribute__((ext_vector_type(4)));

__device__ __forceinline__ unsigned int pack_f16(float a, float b) {
    auto p = __builtin_amdgcn_cvt_pkrtz(a, b);          // __fp16 ext_vector(2)
    union { decltype(p) h; unsigned int u; } cv{p};
    return cv.u;
}
__device__ __forceinline__ f16x8 u4_to_h8(uint4 v) {
    union { uint4 u; f16x8 h; } x; x.u = v; return x.h;
}
__device__ __forceinline__ uint4 h8_to_u4(f16x8 h) {
    union { f16x8 h; uint4 u; } x; x.h = h; return x.u;
}

// ps = 2*log2(e)*x (pre-scaled via weight fold); r = 1/(e^{2x}+1); tanh = 1-2r
__device__ __forceinline__ float sig_r(float ps) {
    float e = __builtin_amdgcn_exp2f(ps);
    return __builtin_amdgcn_rcpf(e + 1.0f);
}
__device__ __forceinline__ float tanh_from_scaled(float ps) {
    return __builtin_fmaf(-2.0f, sig_r(ps), 1.0f);
}

__global__ __launch_bounds__(256, 5) void fans_mfma_kernel(
    const float* __restrict__ x_f, const float* __restrict__ x_b,
    const float* __restrict__ u,   const float* __restrict__ W0,
    const float* __restrict__ W1,  const float* __restrict__ W2,
    float* __restrict__ out)
{
    __shared__ __align__(16) uint4 zplA[256];              // 4 KB: z dwords 0..3
    __shared__ __align__(16) uint2 zplB[256];              // 2 KB: u pair (dw 4,5)
    __shared__ __align__(16) unsigned int Hd[4][16][36];   // 9 KB, stride 144B
    __shared__ __align__(16) uint4 sA0[4][32];             // 2 KB: [t][q*16+c], q<2
    __shared__ __align__(16) uint4 sA1[8][64];             // 8 KB: [ks*4+t][lane]

    const int s   = blockIdx.y;
    const int tid = threadIdx.x;
    const int b0  = blockIdx.x * (256 * CHUNK);

    const int lid = tid & 63;
    const int w   = tid >> 6;     // wave id; wave w owns local rows [64w,64w+64)
    const int c   = lid & 15;
    const int q   = lid >> 4;

    // ---- wave 0 stages weight fragments into LDS (identical for all waves) ----
    if (tid < 64) {
        // Layer1 A-frag: A[m = feat 16t+c][k = 8q+j] = W0[s][feat][k]*SCALE (k<12)
        if (q < 2) {
            const float* w0s = W0 + s * 768;
            #pragma unroll
            for (int t = 0; t < 4; ++t) {
                f16x8 v;
                #pragma unroll
                for (int j = 0; j < 8; ++j) {
                    const int k = 8 * q + j;
                    v[j] = (_Float16)((k < 12) ? w0s[(16 * t + c) * 12 + k] * TANH_SCALE : 0.0f);
                }
                sA0[t][lid] = h8_to_u4(v);          // lid = q*16+c < 32
            }
        }
        // Layer2 A-frag: A[m = feat_out 16t+c][k = 32ks+8q+j] = W1[s][o][h]*SCALE
        const float* w1s = W1 + s * 4096;
        #pragma unroll
        for (int ks = 0; ks < 2; ++ks) {
            #pragma unroll
            for (int t = 0; t < 4; ++t) {
                const float4* p = (const float4*)(w1s + (16 * t + c) * 64 + 32 * ks + 8 * q);
                const float4 v0 = p[0], v1 = p[1];
                f16x8 v = {(_Float16)(v0.x * TANH_SCALE), (_Float16)(v0.y * TANH_SCALE),
                           (_Float16)(v0.z * TANH_SCALE), (_Float16)(v0.w * TANH_SCALE),
                           (_Float16)(v1.x * TANH_SCALE), (_Float16)(v1.y * TANH_SCALE),
                           (_Float16)(v1.z * TANH_SCALE), (_Float16)(v1.w * TANH_SCALE)};
                sA1[ks * 4 + t][lid] = h8_to_u4(v);
            }
        }
    }

    // W2 fold (regs, all threads): dx = sum(w2) + sum_o r_o * (-2*w2_o)
    float w2n[16];
    float sumw2 = 0.0f;
    {
        const float* w2s = W2 + s * 64;
        #pragma unroll
        for (int t = 0; t < 4; ++t)
            #pragma unroll
            for (int r = 0; r < 4; ++r) {
                const float v = w2s[16 * t + 4 * q + r];
                w2n[4 * t + r] = -2.0f * v;
                sumw2 += v;
            }
    }

    __syncthreads();   // one barrier per block: fragment staging visible

    const int wrap = (s > 8) ? (s - 8) : 0;   // IDX[s] = {0..wrap-1}++{s..15}

    #pragma unroll 1
    for (int ch = 0; ch < CHUNK; ++ch) {
        const int rbase = b0 + ch * 256;

        // ---- phase 1: gather z for own row, pack, write planes ----
        {
            const int row = rbase + tid;
            float zs[8];
            #pragma unroll
            for (int j = 0; j < 8; ++j) {
                const int idx = (j < wrap) ? j : (s + j - wrap);  // uniform
                zs[j] = (idx < 8) ? x_f[row * 8 + idx] : x_b[row * 8 + (idx - 8)];
            }
            const float4 uv = *(const float4*)(u + row * 4);
            zplA[tid] = make_uint4(pack_f16(zs[0], zs[1]), pack_f16(zs[2], zs[3]),
                                   pack_f16(zs[4], zs[5]), pack_f16(zs[6], zs[7]));
            zplB[tid] = make_uint2(pack_f16(uv.x, uv.y), pack_f16(uv.z, uv.w));
        }
        // No barrier: wave w reads only rows [64w,64w+64) which it wrote itself.

        // ---- phase 2: 4 M-tiles of 16 rows (own wave's rows only) ----
        #pragma unroll
        for (int m = 0; m < 4; ++m) {
            const int rowb = 64 * w + 16 * m;

            // z B-frag: B[k = 8q+j][n = row c]; k>=12 zero
            f16x8 zf = {0, 0, 0, 0, 0, 0, 0, 0};
            if (q == 0) {
                zf = u4_to_h8(zplA[rowb + c]);
            } else if (q == 1) {
                const uint2 b = zplB[rowb + c];
                zf = u4_to_h8(make_uint4(b.x, b.y, 0u, 0u));
            }

            // layer 1: C[row = feat 16t+4q+r][col = batch row c], pre-scaled
            f32x4 c1[4];
            #pragma unroll
            for (int t = 0; t < 4; ++t) {
                f16x8 a0t = {0, 0, 0, 0, 0, 0, 0, 0};
                if (q < 2) a0t = u4_to_h8(sA0[t][lid]);
                c1[t] = __builtin_amdgcn_mfma_f32_16x16x32_f16(
                    a0t, zf, (f32x4){0.f, 0.f, 0.f, 0.f}, 0, 0, 0);
            }

            // tanh -> pack -> LDS: dword P = 8t+2q holds feats (16t+4q, +1)
            #pragma unroll
            for (int t = 0; t < 4; ++t) {
                *(uint2*)&Hd[w][c][8 * t + 2 * q] =
                    make_uint2(pack_f16(tanh_from_scaled(c1[t][0]), tanh_from_scaled(c1[t][1])),
                               pack_f16(tanh_from_scaled(c1[t][2]), tanh_from_scaled(c1[t][3])));
            }

            // layer 2: B-frag[k = 32ks+8q+j][n = c] = Hd dwords 16ks+4q+0..3
            f32x4 c2[4] = {{0.f, 0.f, 0.f, 0.f}, {0.f, 0.f, 0.f, 0.f},
                           {0.f, 0.f, 0.f, 0.f}, {0.f, 0.f, 0.f, 0.f}};
            #pragma unroll
            for (int ks = 0; ks < 2; ++ks) {
                const f16x8 hb = u4_to_h8(*(const uint4*)&Hd[w][c][16 * ks + 4 * q]);
                #pragma unroll
                for (int t = 0; t < 4; ++t) {
                    const f16x8 a1t = u4_to_h8(sA1[ks * 4 + t][lid]);
                    c2[t] = __builtin_amdgcn_mfma_f32_16x16x32_f16(a1t, hb, c2[t], 0, 0, 0);
                }
            }

            // layer 3: acc = sum(w2) + sum_o r_o * (-2 w2_o); reduce over quads
            float acc = sumw2;
            #pragma unroll
            for (int t = 0; t < 4; ++t)
                #pragma unroll
                for (int r = 0; r < 4; ++r)
                    acc = __builtin_fmaf(sig_r(c2[t][r]), w2n[4 * t + r], acc);
            acc += __shfl_xor(acc, 16);
            acc += __shfl_xor(acc, 32);

            if (lid < 16)
                out[(rbase + rowb + lid) * N_STATES + s] = acc;
        }
    }
}

extern "C" void kernel_launch(void* const* d_in, const int* in_sizes, int n_in,
                              void* d_out, int out_size, void* d_ws, size_t ws_size,
                              hipStream_t stream) {
    const float* x_f = (const float*)d_in[0];
    const float* x_b = (const float*)d_in[1];
    const float* u   = (const float*)d_in[2];
    const float* W0  = (const float*)d_in[3];
    const float* W1  = (const float*)d_in[4];
    const float* W2  = (const float*)d_in[5];
    float* out = (float*)d_out;

    const int nb = in_sizes[0] / 8;                 // 131072 = 128 * 1024
    dim3 grid(nb / (256 * CHUNK), N_STATES);        // (128, 16) = 2048 blocks
    fans_mfma_kernel<<<grid, 256, 0, stream>>>(x_f, x_b, u, W0, W1, W2, out);
}